// Round 15
// baseline (2675.361 us; speedup 1.0000x reference)
//
#include <hip/hip_runtime.h>

// MDN-RNN persistent kernel for MI355X (gfx950).  R15 = R14 + double-buffered
// h_s (1 barrier/step) + spin-first poll.
// B=128, T=1000, D_IN=35, H=512, OUT=480.
// 8 batch-groups (16 batches) x 32 h-slice WGs = 256 WGs, 1/CU.
// Exchange (R14-proven): h(t) -> buf[t%3], full-line slice-major u64 words of
// 4 bf16; h in (-1,1) => ~0ull sentinel is unambiguous. Producer wave resets
// its own words of buf[(t+1)%3] (dead h(t-2)) at step-top; WAIT_VM before
// publish orders reset < publish (acks land under MFMA). Consumers poll
// exactly their own 4 data words (spin 2 rounds, then s_sleep backoff), then
// ds_write into hs_next (OTHER LDS buffer than the one being read) ->
// WAIT_LGKM -> single barrier. Reads(t) of hs_cur precede barrier(t);
// that buffer is only rewritten in exchange(t+1): no write-after-read hazard.
// Lessons: R1/R3 no cache-wide fences; R5/R6+R14 data-as-flag needs clean
// skeleton + no amplification; R7 backoff; R8 never trust placement; R9/R10
// raw barriers + typed waits + reg B/x; R11/R12 full-line publishes; R13
// no shared flag lines.

#define NGRP   8
#define NSLICE 32
#define GB     16
#define HH     512
#define TT     1000
#define DIN    35
#define OUTC   480
#define ODC    15
#define HWORDS 2048      // u64 words per group h snapshot (16*512/4)
#define GSTR   20        // gbuf/pbuf row stride in floats

typedef __bf16 bf16x8 __attribute__((ext_vector_type(8)));
typedef float  f32x4  __attribute__((ext_vector_type(4)));
typedef unsigned short u16;
typedef unsigned int   u32;
typedef unsigned long long u64;
#define SENT (~0ull)

__device__ __forceinline__ u16 f2bf(float x) {
    u32 u = __float_as_uint(x);
    u += 0x7FFFu + ((u >> 16) & 1u);
    return (u16)(u >> 16);
}
__device__ __forceinline__ float sigf(float x) { return 1.0f / (1.0f + __expf(-x)); }
__device__ __forceinline__ float tanh_fast(float x) {
    float ax = fabsf(x);
    float e = __expf(-2.0f * ax);
    return copysignf((1.0f - e) / (1.0f + e), x);
}
__device__ __forceinline__ u32 pk2f(float a, float b) {
    return (u32)f2bf(a) | ((u32)f2bf(b) << 16);
}

union bf8u { u32 u[4]; bf16x8 v; };

#define BARRIER() do { asm volatile("" ::: "memory"); \
                       __builtin_amdgcn_s_barrier(); \
                       asm volatile("" ::: "memory"); \
                       __builtin_amdgcn_sched_barrier(0); } while (0)
#define WAIT_LGKM() do { asm volatile("s_waitcnt lgkmcnt(0)" ::: "memory"); \
                         __builtin_amdgcn_sched_barrier(0); } while (0)
#define WAIT_VM()   do { asm volatile("s_waitcnt vmcnt(0)" ::: "memory"); \
                         __builtin_amdgcn_sched_barrier(0); } while (0)

#define MFMA16(a, b, c) __builtin_amdgcn_mfma_f32_16x16x32_bf16((a), (b), (c), 0, 0, 0)

__global__ void __launch_bounds__(512, 1)
mdn_kernel(const float* __restrict__ inp, const float* __restrict__ Wk,
           const float* __restrict__ Wr,  const float* __restrict__ bg,
           const float* __restrict__ Wd,  const float* __restrict__ bd,
           float* __restrict__ out, u64* __restrict__ hbuf)
{
    __shared__ __attribute__((aligned(16))) u16  wr_s[64 * HH];   // dead after preamble
    __shared__ __attribute__((aligned(16))) u16  wk_s[64 * 64];   // dead after preamble
    __shared__ __attribute__((aligned(16))) u16  wd_s[16 * HH];   // dead after preamble
    __shared__ __attribute__((aligned(16))) u16  hsA[GB * HH];    // h double buffer A
    __shared__ __attribute__((aligned(16))) u16  hsB[GB * HH];    // h double buffer B
    __shared__ __attribute__((aligned(16))) float gbuf[4 * 16 * GSTR];      // [w][batch][c]
    __shared__ __attribute__((aligned(16))) float pbuf[2 * 4 * 16 * GSTR];  // [par][kw][batch][oo]

    const int tid  = threadIdx.x;
    const int lane = tid & 63;
    const int wave = tid >> 6;
    const int g    = blockIdx.x & 7;    // batch group (XCD-affine under round-robin)
    const int s    = blockIdx.x >> 3;   // h-slice 0..31
    const int m16  = lane & 15;
    const int kq   = lane >> 4;

    // ---------------- preamble: weight staging + hsA zero ----------------
    {
        int n = tid & 63;
        int q = n >> 4, j4 = n & 15;
        int col = q * HH + s * 16 + j4;
        for (int k = tid >> 6; k < HH; k += 8)
            wr_s[n * HH + (k ^ ((n & 7) << 3))] = f2bf(Wr[(size_t)k * 2048 + col]);
        for (int k = tid >> 6; k < 64; k += 8)
            wk_s[n * 64 + (k ^ ((n & 7) << 3))] = f2bf(k < DIN ? Wk[(size_t)k * 2048 + col] : 0.0f);
    }
    {
        int n = tid & 15;
        for (int k = tid >> 4; k < HH; k += 32)
            wd_s[n * HH + (k ^ ((n & 7) << 3))] =
                f2bf(n < ODC ? Wd[(size_t)k * OUTC + s * ODC + n] : 0.0f);
    }
    for (int i = tid; i < GB * HH / 4; i += 512) ((u64*)hsA)[i] = 0ull;  // h_{-1}=0
    __syncthreads();   // one-time full sync

    // ---------------- B-fragments to registers (R11 gate-col mapping) ----------------
    bf16x8 bfr[18];
    if (wave < 4) {
        // wave owns hcols 4w..4w+3, all 4 gates: B-col m16 <-> (q=m16&3, e=m16>>2)
        int nloc = (m16 & 3) * 16 + 4 * wave + (m16 >> 2);   // local gate col 0..63
        #pragma unroll
        for (int ks = 0; ks < 16; ++ks) {
            int k0 = 32 * ks + 8 * kq;
            bfr[ks] = *(const bf16x8*)(&wr_s[nloc * HH + (k0 ^ ((nloc & 7) << 3))]);
        }
        #pragma unroll
        for (int i = 0; i < 2; ++i) {
            int k0 = 32 * i + 8 * kq;
            bfr[16 + i] = *(const bf16x8*)(&wk_s[nloc * 64 + (k0 ^ ((nloc & 7) << 3))]);
        }
    } else {
        int w4 = wave - 4;
        #pragma unroll
        for (int kk = 0; kk < 4; ++kk) {
            int k0 = w4 * 128 + 32 * kk + 8 * kq;
            bfr[kk] = *(const bf16x8*)(&wd_s[m16 * HH + (k0 ^ ((m16 & 7) << 3))]);
        }
    }

    // ---------------- per-lane state ----------------
    float c_reg = 0.f;
    float bi = 0.f, bff = 0.f, bgg = 0.f, boo = 0.f, bdv = 0.f;
    const int cb = lane & 15;          // gate waves: cell batch
    const int ce = lane >> 4;          // gate waves: cell hcol-in-wave (0..3)
    if (wave < 4) {
        int jj = 4 * wave + ce;        // cell hcol 0..15
        int scol = s * 16 + jj;
        bi  = bg[0 * HH + scol];
        bff = bg[1 * HH + scol];
        bgg = bg[2 * HH + scol];
        boo = bg[3 * HH + scol];
    } else {
        int oo = lane & 15;
        if (oo < ODC) bdv = bd[s * ODC + oo];
    }

    // x registers: gate lane (m16=batch, kq=k-section) owns x[m16][kq*8..+7] (+32..34, kq==0)
    float xr[8];
    float xe0 = 0.f, xe1 = 0.f, xe2 = 0.f;
    #pragma unroll
    for (int i = 0; i < 8; ++i) xr[i] = 0.f;
    if (wave < 4) {
        const float* ip = inp + ((size_t)(g * GB + m16) * TT + 0) * DIN;
        #pragma unroll
        for (int i = 0; i < 8; ++i) xr[i] = ip[kq * 8 + i];
        if (kq == 0) { xe0 = ip[32]; xe1 = ip[33]; xe2 = ip[34]; }
    }
    __syncthreads();

    for (int t = 0; t <= TT + 1; ++t) {
        // invariant at top: hs_cur = h_{t-1}; xr = x_t (gate waves)
        u16* hs_cur = (t & 1) ? hsB : hsA;
        u16* hs_nxt = (t & 1) ? hsA : hsB;

        if (wave < 4) {
            if (t < TT) {
                // ---- sentinel-reset own words of buf[(t+1)%3] (dead h_{t-2}) ----
                if (ce == 0) {
                    u64* rp = hbuf + (size_t)((t + 1) % 3) * (NGRP * HWORDS) + g * HWORDS
                                  + s * 64 + wave * 16 + cb;
                    __hip_atomic_store(rp, SENT, __ATOMIC_RELAXED, __HIP_MEMORY_SCOPE_AGENT);
                }
                // ---- gate MFMA ----
                bf8u a0, a1;
                a0.u[0] = pk2f(xr[0], xr[1]); a0.u[1] = pk2f(xr[2], xr[3]);
                a0.u[2] = pk2f(xr[4], xr[5]); a0.u[3] = pk2f(xr[6], xr[7]);
                a1.u[0] = (kq == 0) ? pk2f(xe0, xe1) : 0u;
                a1.u[1] = (kq == 0) ? pk2f(xe2, 0.f) : 0u;
                a1.u[2] = 0u; a1.u[3] = 0u;
                f32x4 acc0 = {0,0,0,0}, acc1 = {0,0,0,0};
                acc0 = MFMA16(a0.v, bfr[16], acc0);
                acc1 = MFMA16(a1.v, bfr[17], acc1);
                #pragma unroll
                for (int ks = 0; ks < 16; ks += 2) {
                    int k0 = 32 * ks + 8 * kq;
                    bf16x8 a = *(const bf16x8*)(&hs_cur[m16 * HH + (k0 ^ ((m16 & 7) << 3))]);
                    acc0 = MFMA16(a, bfr[ks], acc0);
                    int k1 = 32 * (ks + 1) + 8 * kq;
                    bf16x8 a2 = *(const bf16x8*)(&hs_cur[m16 * HH + (k1 ^ ((m16 & 7) << 3))]);
                    acc1 = MFMA16(a2, bfr[ks + 1], acc1);
                }
                // ---- same-wave D roundtrip ----
                #pragma unroll
                for (int j = 0; j < 4; ++j)
                    gbuf[wave * 16 * GSTR + (kq * 4 + j) * GSTR + m16] = acc0[j] + acc1[j];
                WAIT_LGKM();
                f32x4 gv = *(const f32x4*)(&gbuf[wave * 16 * GSTR + cb * GSTR + 4 * ce]);
                // ---- scalar LSTM cell ----
                float iv = gv[0] + bi, fv = gv[1] + bff;
                float gg2 = gv[2] + bgg, ov = gv[3] + boo;
                c_reg = sigf(fv) * c_reg + sigf(iv) * tanh_fast(gg2);
                float h = sigf(ov) * tanh_fast(c_reg);
                // ---- pack 4 hcols; drain (resets ack'd under MFMA); publish ----
                u32 hb32 = (u32)f2bf(h);
                u32 o1 = (u32)__shfl_xor((int)hb32, 16);
                u32 pair = ((ce & 1) == 0) ? (hb32 | (o1 << 16)) : (o1 | (hb32 << 16));
                u32 o2 = (u32)__shfl_xor((int)pair, 32);
                WAIT_VM();                          // orders prior resets < this publish
                if (ce == 0) {
                    u64 w64 = (u64)pair | ((u64)o2 << 32);   // hcols 4w..4w+3
                    u64* dst = hbuf + (size_t)(t % 3) * (NGRP * HWORDS) + g * HWORDS
                                  + s * 64 + wave * 16 + cb;  // full-line slice-major
                    __hip_atomic_store(dst, w64, __ATOMIC_RELAXED, __HIP_MEMORY_SCOPE_AGENT);
                }
                // x(t+1) prefetch (rides across barriers)
                if (t + 1 < TT) {
                    const float* ip = inp + ((size_t)(g * GB + m16) * TT + (t + 1)) * DIN;
                    #pragma unroll
                    for (int i = 0; i < 8; ++i) xr[i] = ip[kq * 8 + i];
                    if (kq == 0) { xe0 = ip[32]; xe1 = ip[33]; xe2 = ip[34]; }
                }
            }
        } else {
            int w4 = wave - 4;
            if (t >= 2) {
                // ---- reduce + store row t-2 from pbuf[prev] (barrier-ordered) ----
                int bb = 4 * w4 + (lane >> 4);
                int oo = lane & 15;
                int par = ((t & 1) ^ 1) * 4 * 16 * GSTR;
                float v = pbuf[par + 0 * 16 * GSTR + bb * GSTR + oo]
                        + pbuf[par + 1 * 16 * GSTR + bb * GSTR + oo]
                        + pbuf[par + 2 * 16 * GSTR + bb * GSTR + oo]
                        + pbuf[par + 3 * 16 * GSTR + bb * GSTR + oo] + bdv;
                if (oo < ODC)
                    out[((size_t)(g * GB + bb) * TT + (t - 2)) * OUTC + s * ODC + oo] = v;
            }
            if (t >= 1 && t <= TT) {
                // ---- out-GEMM partials row t-1 (hs_cur = h_{t-1}) -> pbuf[t&1] ----
                f32x4 acc0 = {0,0,0,0}, acc1 = {0,0,0,0};
                #pragma unroll
                for (int kk = 0; kk < 4; kk += 2) {
                    int k0 = w4 * 128 + 32 * kk + 8 * kq;
                    bf16x8 a = *(const bf16x8*)(&hs_cur[m16 * HH + (k0 ^ ((m16 & 7) << 3))]);
                    acc0 = MFMA16(a, bfr[kk], acc0);
                    int k1 = w4 * 128 + 32 * (kk + 1) + 8 * kq;
                    bf16x8 a2 = *(const bf16x8*)(&hs_cur[m16 * HH + (k1 ^ ((m16 & 7) << 3))]);
                    acc1 = MFMA16(a2, bfr[kk + 1], acc1);
                }
                #pragma unroll
                for (int j = 0; j < 4; ++j)
                    pbuf[(t & 1) * 4 * 16 * GSTR + w4 * 16 * GSTR + (kq * 4 + j) * GSTR + m16]
                        = acc0[j] + acc1[j];
            }
        }

        // ========== exchange: poll own 4 data words -> hs_nxt; ONE barrier ==========
        if (t < TT) {
            const u64* bp = hbuf + (size_t)(t % 3) * (NGRP * HWORDS) + g * HWORDS;
            const int L0 = tid, L1 = tid + 512, L2 = tid + 1024, L3 = tid + 1536;
            u64 v0 = SENT, v1 = SENT, v2 = SENT, v3 = SENT;
            int spins = 0;
            while (true) {
                if (v0 == SENT) v0 = __hip_atomic_load(bp + L0, __ATOMIC_RELAXED, __HIP_MEMORY_SCOPE_AGENT);
                if (v1 == SENT) v1 = __hip_atomic_load(bp + L1, __ATOMIC_RELAXED, __HIP_MEMORY_SCOPE_AGENT);
                if (v2 == SENT) v2 = __hip_atomic_load(bp + L2, __ATOMIC_RELAXED, __HIP_MEMORY_SCOPE_AGENT);
                if (v3 == SENT) v3 = __hip_atomic_load(bp + L3, __ATOMIC_RELAXED, __HIP_MEMORY_SCOPE_AGENT);
                if (__all((int)(v0 != SENT && v1 != SENT && v2 != SENT && v3 != SENT))) break;
                if (++spins > (1 << 20)) break;            // bounded bail-out: no hangs
                if (spins > 2) __builtin_amdgcn_s_sleep(1);  // spin-first, then backoff
            }
            // scatter into hs_nxt (OTHER buffer than the one read this step)
            {
                u64 vv[4] = {v0, v1, v2, v3};
                #pragma unroll
                for (int i = 0; i < 4; ++i) {
                    int L = tid + i * 512;
                    int b    = L & 15;
                    int kcol = (L >> 6) * 16 + 4 * ((L >> 4) & 3);
                    *(u64*)(&hs_nxt[b * HH + (kcol ^ ((b & 7) << 3))]) = vv[i];
                }
            }
            WAIT_LGKM(); BARRIER();                        // single barrier: hs_nxt ready
        } else {
            // tail steps (t = TT, TT+1): order pbuf handoff for delayed reduce
            WAIT_LGKM(); BARRIER();
        }
    }
}

extern "C" void kernel_launch(void* const* d_in, const int* in_sizes, int n_in,
                              void* d_out, int out_size, void* d_ws, size_t ws_size,
                              hipStream_t stream) {
    const float* inp = (const float*)d_in[0];
    const float* Wk  = (const float*)d_in[1];
    const float* Wr  = (const float*)d_in[2];
    const float* bg  = (const float*)d_in[3];
    const float* Wd  = (const float*)d_in[4];
    const float* bd  = (const float*)d_in[5];
    float* out = (float*)d_out;

    // ws: h exchange, 3 rotating buffers x 8 groups x 2048 u64 = 384 KB.
    // Memset 0xFF (sentinel) every launch: bf16 h values are never NaN, so
    // ~0ull words unambiguously mean "not yet written this launch".
    u64* hbuf = (u64*)d_ws;
    size_t zbytes = (size_t)3 * NGRP * HWORDS * sizeof(u64);
    hipMemsetAsync(d_ws, 0xFF, zbytes, stream);

    hipLaunchKernelGGL(mdn_kernel, dim3(NGRP * NSLICE), dim3(512), 0, stream,
                       inp, Wk, Wr, bg, Wd, bd, out, hbuf);
}

// Round 16
// 2409.534 us; speedup vs baseline: 1.1103x; 1.1103x over previous
//
#include <hip/hip_runtime.h>

// MDN-RNN persistent kernel for MI355X (gfx950).  R16 = R14 exchange + R15's
// double-buffered h_s (1 barrier/step), poll reverted to sleep-every-round.
// B=128, T=1000, D_IN=35, H=512, OUT=480.
// 8 batch-groups (16 batches) x 32 h-slice WGs = 256 WGs, 1/CU.
// Exchange (R14-proven): h(t) -> buf[t%3], full-line slice-major u64 words of
// 4 bf16; h in (-1,1) => ~0ull sentinel unambiguous. Producer wave resets its
// own words of buf[(t+1)%3] (dead h(t-2)) at step-top; WAIT_VM before publish
// orders reset < publish (acks land under MFMA). Consumers poll exactly their
// own 4 data words with s_sleep(1) EVERY round (R15 lesson: spin-first polling
// floods the MALL with reads and delays the very stores being polled — poll
// cadence must be throttled even on own-data), then ds_write into hs_nxt
// (other LDS buffer than the one being read) -> WAIT_LGKM -> single barrier.
// Reads(t) of hs_cur precede barrier(t); hs_cur is only rewritten in
// exchange(t+1): no write-after-read hazard.
// Lessons: R1/R3 no cache-wide fences; R5/R6+R14 data-as-flag on clean
// skeleton; R7+R15 poll backoff ALWAYS; R8 never trust placement; R9/R10 raw
// barriers + typed waits + reg B/x; R11/R12 full-line publishes; R13 no
// shared flag lines.

#define NGRP   8
#define NSLICE 32
#define GB     16
#define HH     512
#define TT     1000
#define DIN    35
#define OUTC   480
#define ODC    15
#define HWORDS 2048      // u64 words per group h snapshot (16*512/4)
#define GSTR   20        // gbuf/pbuf row stride in floats

typedef __bf16 bf16x8 __attribute__((ext_vector_type(8)));
typedef float  f32x4  __attribute__((ext_vector_type(4)));
typedef unsigned short u16;
typedef unsigned int   u32;
typedef unsigned long long u64;
#define SENT (~0ull)

__device__ __forceinline__ u16 f2bf(float x) {
    u32 u = __float_as_uint(x);
    u += 0x7FFFu + ((u >> 16) & 1u);
    return (u16)(u >> 16);
}
__device__ __forceinline__ float sigf(float x) { return 1.0f / (1.0f + __expf(-x)); }
__device__ __forceinline__ float tanh_fast(float x) {
    float ax = fabsf(x);
    float e = __expf(-2.0f * ax);
    return copysignf((1.0f - e) / (1.0f + e), x);
}
__device__ __forceinline__ u32 pk2f(float a, float b) {
    return (u32)f2bf(a) | ((u32)f2bf(b) << 16);
}

union bf8u { u32 u[4]; bf16x8 v; };

#define BARRIER() do { asm volatile("" ::: "memory"); \
                       __builtin_amdgcn_s_barrier(); \
                       asm volatile("" ::: "memory"); \
                       __builtin_amdgcn_sched_barrier(0); } while (0)
#define WAIT_LGKM() do { asm volatile("s_waitcnt lgkmcnt(0)" ::: "memory"); \
                         __builtin_amdgcn_sched_barrier(0); } while (0)
#define WAIT_VM()   do { asm volatile("s_waitcnt vmcnt(0)" ::: "memory"); \
                         __builtin_amdgcn_sched_barrier(0); } while (0)

#define MFMA16(a, b, c) __builtin_amdgcn_mfma_f32_16x16x32_bf16((a), (b), (c), 0, 0, 0)

__global__ void __launch_bounds__(512, 1)
mdn_kernel(const float* __restrict__ inp, const float* __restrict__ Wk,
           const float* __restrict__ Wr,  const float* __restrict__ bg,
           const float* __restrict__ Wd,  const float* __restrict__ bd,
           float* __restrict__ out, u64* __restrict__ hbuf)
{
    __shared__ __attribute__((aligned(16))) u16  wr_s[64 * HH];   // dead after preamble
    __shared__ __attribute__((aligned(16))) u16  wk_s[64 * 64];   // dead after preamble
    __shared__ __attribute__((aligned(16))) u16  wd_s[16 * HH];   // dead after preamble
    __shared__ __attribute__((aligned(16))) u16  hsA[GB * HH];    // h double buffer A
    __shared__ __attribute__((aligned(16))) u16  hsB[GB * HH];    // h double buffer B
    __shared__ __attribute__((aligned(16))) float gbuf[4 * 16 * GSTR];      // [w][batch][c]
    __shared__ __attribute__((aligned(16))) float pbuf[2 * 4 * 16 * GSTR];  // [par][kw][batch][oo]

    const int tid  = threadIdx.x;
    const int lane = tid & 63;
    const int wave = tid >> 6;
    const int g    = blockIdx.x & 7;    // batch group (XCD-affine under round-robin)
    const int s    = blockIdx.x >> 3;   // h-slice 0..31
    const int m16  = lane & 15;
    const int kq   = lane >> 4;

    // ---------------- preamble: weight staging + hsA zero ----------------
    {
        int n = tid & 63;
        int q = n >> 4, j4 = n & 15;
        int col = q * HH + s * 16 + j4;
        for (int k = tid >> 6; k < HH; k += 8)
            wr_s[n * HH + (k ^ ((n & 7) << 3))] = f2bf(Wr[(size_t)k * 2048 + col]);
        for (int k = tid >> 6; k < 64; k += 8)
            wk_s[n * 64 + (k ^ ((n & 7) << 3))] = f2bf(k < DIN ? Wk[(size_t)k * 2048 + col] : 0.0f);
    }
    {
        int n = tid & 15;
        for (int k = tid >> 4; k < HH; k += 32)
            wd_s[n * HH + (k ^ ((n & 7) << 3))] =
                f2bf(n < ODC ? Wd[(size_t)k * OUTC + s * ODC + n] : 0.0f);
    }
    for (int i = tid; i < GB * HH / 4; i += 512) ((u64*)hsA)[i] = 0ull;  // h_{-1}=0
    __syncthreads();   // one-time full sync

    // ---------------- B-fragments to registers (R11 gate-col mapping) ----------------
    bf16x8 bfr[18];
    if (wave < 4) {
        // wave owns hcols 4w..4w+3, all 4 gates: B-col m16 <-> (q=m16&3, e=m16>>2)
        int nloc = (m16 & 3) * 16 + 4 * wave + (m16 >> 2);   // local gate col 0..63
        #pragma unroll
        for (int ks = 0; ks < 16; ++ks) {
            int k0 = 32 * ks + 8 * kq;
            bfr[ks] = *(const bf16x8*)(&wr_s[nloc * HH + (k0 ^ ((nloc & 7) << 3))]);
        }
        #pragma unroll
        for (int i = 0; i < 2; ++i) {
            int k0 = 32 * i + 8 * kq;
            bfr[16 + i] = *(const bf16x8*)(&wk_s[nloc * 64 + (k0 ^ ((nloc & 7) << 3))]);
        }
    } else {
        int w4 = wave - 4;
        #pragma unroll
        for (int kk = 0; kk < 4; ++kk) {
            int k0 = w4 * 128 + 32 * kk + 8 * kq;
            bfr[kk] = *(const bf16x8*)(&wd_s[m16 * HH + (k0 ^ ((m16 & 7) << 3))]);
        }
    }

    // ---------------- per-lane state ----------------
    float c_reg = 0.f;
    float bi = 0.f, bff = 0.f, bgg = 0.f, boo = 0.f, bdv = 0.f;
    const int cb = lane & 15;          // gate waves: cell batch
    const int ce = lane >> 4;          // gate waves: cell hcol-in-wave (0..3)
    if (wave < 4) {
        int jj = 4 * wave + ce;        // cell hcol 0..15
        int scol = s * 16 + jj;
        bi  = bg[0 * HH + scol];
        bff = bg[1 * HH + scol];
        bgg = bg[2 * HH + scol];
        boo = bg[3 * HH + scol];
    } else {
        int oo = lane & 15;
        if (oo < ODC) bdv = bd[s * ODC + oo];
    }

    // x registers: gate lane (m16=batch, kq=k-section) owns x[m16][kq*8..+7] (+32..34, kq==0)
    float xr[8];
    float xe0 = 0.f, xe1 = 0.f, xe2 = 0.f;
    #pragma unroll
    for (int i = 0; i < 8; ++i) xr[i] = 0.f;
    if (wave < 4) {
        const float* ip = inp + ((size_t)(g * GB + m16) * TT + 0) * DIN;
        #pragma unroll
        for (int i = 0; i < 8; ++i) xr[i] = ip[kq * 8 + i];
        if (kq == 0) { xe0 = ip[32]; xe1 = ip[33]; xe2 = ip[34]; }
    }
    __syncthreads();

    for (int t = 0; t <= TT + 1; ++t) {
        // invariant at top: hs_cur = h_{t-1}; xr = x_t (gate waves)
        u16* hs_cur = (t & 1) ? hsB : hsA;
        u16* hs_nxt = (t & 1) ? hsA : hsB;

        if (wave < 4) {
            if (t < TT) {
                // ---- sentinel-reset own words of buf[(t+1)%3] (dead h_{t-2}) ----
                if (ce == 0) {
                    u64* rp = hbuf + (size_t)((t + 1) % 3) * (NGRP * HWORDS) + g * HWORDS
                                  + s * 64 + wave * 16 + cb;
                    __hip_atomic_store(rp, SENT, __ATOMIC_RELAXED, __HIP_MEMORY_SCOPE_AGENT);
                }
                // ---- gate MFMA ----
                bf8u a0, a1;
                a0.u[0] = pk2f(xr[0], xr[1]); a0.u[1] = pk2f(xr[2], xr[3]);
                a0.u[2] = pk2f(xr[4], xr[5]); a0.u[3] = pk2f(xr[6], xr[7]);
                a1.u[0] = (kq == 0) ? pk2f(xe0, xe1) : 0u;
                a1.u[1] = (kq == 0) ? pk2f(xe2, 0.f) : 0u;
                a1.u[2] = 0u; a1.u[3] = 0u;
                f32x4 acc0 = {0,0,0,0}, acc1 = {0,0,0,0};
                acc0 = MFMA16(a0.v, bfr[16], acc0);
                acc1 = MFMA16(a1.v, bfr[17], acc1);
                #pragma unroll
                for (int ks = 0; ks < 16; ks += 2) {
                    int k0 = 32 * ks + 8 * kq;
                    bf16x8 a = *(const bf16x8*)(&hs_cur[m16 * HH + (k0 ^ ((m16 & 7) << 3))]);
                    acc0 = MFMA16(a, bfr[ks], acc0);
                    int k1 = 32 * (ks + 1) + 8 * kq;
                    bf16x8 a2 = *(const bf16x8*)(&hs_cur[m16 * HH + (k1 ^ ((m16 & 7) << 3))]);
                    acc1 = MFMA16(a2, bfr[ks + 1], acc1);
                }
                // ---- same-wave D roundtrip ----
                #pragma unroll
                for (int j = 0; j < 4; ++j)
                    gbuf[wave * 16 * GSTR + (kq * 4 + j) * GSTR + m16] = acc0[j] + acc1[j];
                WAIT_LGKM();
                f32x4 gv = *(const f32x4*)(&gbuf[wave * 16 * GSTR + cb * GSTR + 4 * ce]);
                // ---- scalar LSTM cell ----
                float iv = gv[0] + bi, fv = gv[1] + bff;
                float gg2 = gv[2] + bgg, ov = gv[3] + boo;
                c_reg = sigf(fv) * c_reg + sigf(iv) * tanh_fast(gg2);
                float h = sigf(ov) * tanh_fast(c_reg);
                // ---- pack 4 hcols; drain (resets ack'd under MFMA); publish ----
                u32 hb32 = (u32)f2bf(h);
                u32 o1 = (u32)__shfl_xor((int)hb32, 16);
                u32 pair = ((ce & 1) == 0) ? (hb32 | (o1 << 16)) : (o1 | (hb32 << 16));
                u32 o2 = (u32)__shfl_xor((int)pair, 32);
                WAIT_VM();                          // orders prior resets < this publish
                if (ce == 0) {
                    u64 w64 = (u64)pair | ((u64)o2 << 32);   // hcols 4w..4w+3
                    u64* dst = hbuf + (size_t)(t % 3) * (NGRP * HWORDS) + g * HWORDS
                                  + s * 64 + wave * 16 + cb;  // full-line slice-major
                    __hip_atomic_store(dst, w64, __ATOMIC_RELAXED, __HIP_MEMORY_SCOPE_AGENT);
                }
                // x(t+1) prefetch (rides across barriers)
                if (t + 1 < TT) {
                    const float* ip = inp + ((size_t)(g * GB + m16) * TT + (t + 1)) * DIN;
                    #pragma unroll
                    for (int i = 0; i < 8; ++i) xr[i] = ip[kq * 8 + i];
                    if (kq == 0) { xe0 = ip[32]; xe1 = ip[33]; xe2 = ip[34]; }
                }
            }
        } else {
            int w4 = wave - 4;
            if (t >= 2) {
                // ---- reduce + store row t-2 from pbuf[prev] (barrier-ordered) ----
                int bb = 4 * w4 + (lane >> 4);
                int oo = lane & 15;
                int par = ((t & 1) ^ 1) * 4 * 16 * GSTR;
                float v = pbuf[par + 0 * 16 * GSTR + bb * GSTR + oo]
                        + pbuf[par + 1 * 16 * GSTR + bb * GSTR + oo]
                        + pbuf[par + 2 * 16 * GSTR + bb * GSTR + oo]
                        + pbuf[par + 3 * 16 * GSTR + bb * GSTR + oo] + bdv;
                if (oo < ODC)
                    out[((size_t)(g * GB + bb) * TT + (t - 2)) * OUTC + s * ODC + oo] = v;
            }
            if (t >= 1 && t <= TT) {
                // ---- out-GEMM partials row t-1 (hs_cur = h_{t-1}) -> pbuf[t&1] ----
                f32x4 acc0 = {0,0,0,0}, acc1 = {0,0,0,0};
                #pragma unroll
                for (int kk = 0; kk < 4; kk += 2) {
                    int k0 = w4 * 128 + 32 * kk + 8 * kq;
                    bf16x8 a = *(const bf16x8*)(&hs_cur[m16 * HH + (k0 ^ ((m16 & 7) << 3))]);
                    acc0 = MFMA16(a, bfr[kk], acc0);
                    int k1 = w4 * 128 + 32 * (kk + 1) + 8 * kq;
                    bf16x8 a2 = *(const bf16x8*)(&hs_cur[m16 * HH + (k1 ^ ((m16 & 7) << 3))]);
                    acc1 = MFMA16(a2, bfr[kk + 1], acc1);
                }
                #pragma unroll
                for (int j = 0; j < 4; ++j)
                    pbuf[(t & 1) * 4 * 16 * GSTR + w4 * 16 * GSTR + (kq * 4 + j) * GSTR + m16]
                        = acc0[j] + acc1[j];
            }
        }

        // ========== exchange: poll own 4 data words -> hs_nxt; ONE barrier ==========
        if (t < TT) {
            const u64* bp = hbuf + (size_t)(t % 3) * (NGRP * HWORDS) + g * HWORDS;
            const int L0 = tid, L1 = tid + 512, L2 = tid + 1024, L3 = tid + 1536;
            u64 v0 = SENT, v1 = SENT, v2 = SENT, v3 = SENT;
            int spins = 0;
            while (true) {
                if (v0 == SENT) v0 = __hip_atomic_load(bp + L0, __ATOMIC_RELAXED, __HIP_MEMORY_SCOPE_AGENT);
                if (v1 == SENT) v1 = __hip_atomic_load(bp + L1, __ATOMIC_RELAXED, __HIP_MEMORY_SCOPE_AGENT);
                if (v2 == SENT) v2 = __hip_atomic_load(bp + L2, __ATOMIC_RELAXED, __HIP_MEMORY_SCOPE_AGENT);
                if (v3 == SENT) v3 = __hip_atomic_load(bp + L3, __ATOMIC_RELAXED, __HIP_MEMORY_SCOPE_AGENT);
                if (__all((int)(v0 != SENT && v1 != SENT && v2 != SENT && v3 != SENT))) break;
                if (++spins > (1 << 20)) break;            // bounded bail-out: no hangs
                __builtin_amdgcn_s_sleep(1);               // backoff EVERY round (R15 lesson)
            }
            // scatter into hs_nxt (OTHER buffer than the one read this step)
            {
                u64 vv[4] = {v0, v1, v2, v3};
                #pragma unroll
                for (int i = 0; i < 4; ++i) {
                    int L = tid + i * 512;
                    int b    = L & 15;
                    int kcol = (L >> 6) * 16 + 4 * ((L >> 4) & 3);
                    *(u64*)(&hs_nxt[b * HH + (kcol ^ ((b & 7) << 3))]) = vv[i];
                }
            }
            WAIT_LGKM(); BARRIER();                        // single barrier: hs_nxt ready
        } else {
            // tail steps (t = TT, TT+1): order pbuf handoff for delayed reduce
            WAIT_LGKM(); BARRIER();
        }
    }
}

extern "C" void kernel_launch(void* const* d_in, const int* in_sizes, int n_in,
                              void* d_out, int out_size, void* d_ws, size_t ws_size,
                              hipStream_t stream) {
    const float* inp = (const float*)d_in[0];
    const float* Wk  = (const float*)d_in[1];
    const float* Wr  = (const float*)d_in[2];
    const float* bg  = (const float*)d_in[3];
    const float* Wd  = (const float*)d_in[4];
    const float* bd  = (const float*)d_in[5];
    float* out = (float*)d_out;

    // ws: h exchange, 3 rotating buffers x 8 groups x 2048 u64 = 384 KB.
    // Memset 0xFF (sentinel) every launch: bf16 h values are never NaN, so
    // ~0ull words unambiguously mean "not yet written this launch".
    u64* hbuf = (u64*)d_ws;
    size_t zbytes = (size_t)3 * NGRP * HWORDS * sizeof(u64);
    hipMemsetAsync(d_ws, 0xFF, zbytes, stream);

    hipLaunchKernelGGL(mdn_kernel, dim3(NGRP * NSLICE), dim3(512), 0, stream,
                       inp, Wk, Wr, bg, Wd, bd, out, hbuf);
}

// Round 18
// 2383.997 us; speedup vs baseline: 1.1222x; 1.0107x over previous
//
#include <hip/hip_runtime.h>

// MDN-RNN persistent kernel for MI355X (gfx950).  R18 = exact R16 revert (champion).
// B=128, T=1000, D_IN=35, H=512, OUT=480.  dur ~2.41 ms, absmax 0.0039.
// 8 batch-groups (16 batches) x 32 h-slice WGs = 256 WGs, 1/CU.
// Exchange (R14/R16-proven): h(t) -> buf[t%3], full-line slice-major u64 words
// of 4 bf16; h in (-1,1) => ~0ull sentinel unambiguous. Producer wave resets
// its own words of buf[(t+1)%3] (dead h(t-2)) at step-top; WAIT_VM before
// publish orders reset < publish (acks land under MFMA). Consumers poll
// exactly their own 4 data words with s_sleep(1) every round, then ds_write
// into hs_nxt (other LDS buffer than the one being read) -> WAIT_LGKM ->
// single barrier. Reads(t) of hs_cur precede barrier(t); hs_cur is only
// rewritten in exchange(t+1): no write-after-read hazard.
//
// FINAL LESSON LEDGER:
//  R1/R3: agent-scope acquire/release = buffer_wbl2/inv cache-wide storms; use
//         RELAXED agent atomics (per-access MALL bypass) for all cross-WG data.
//  R5/R6/R14: data-as-flag (sentinel) wins, but ONLY on a clean skeleton
//         (typed waits, full-line layout) and with zero traffic amplification.
//  R7/R15: poll cadence must ALWAYS be throttled (s_sleep every round).
//  R8/R17: gfx950 has no scope between workgroup and agent — per-XCD L2
//         cannot be a software coherence point (sc0 loads miss L2-dirty data);
//         cross-CU comm must pay the MALL round trip. XCD-local exchange dead.
//  R11/R12/R13: publishes must be full-line; no LDS-atomic publisher chains;
//         no shared flag cachelines.
//  R9/R10: raw s_barrier + typed waits (no forced VMEM drains); B-frags and
//         x in registers.
// STRUCTURAL FLOOR: 1000 serial MALL all-gathers; ~1 propagation RT + compute
// + 32-WG jitter per step. Latency-bound, not mem/compute-bound.

#define NGRP   8
#define NSLICE 32
#define GB     16
#define HH     512
#define TT     1000
#define DIN    35
#define OUTC   480
#define ODC    15
#define HWORDS 2048      // u64 words per group h snapshot (16*512/4)
#define GSTR   20        // gbuf/pbuf row stride in floats

typedef __bf16 bf16x8 __attribute__((ext_vector_type(8)));
typedef float  f32x4  __attribute__((ext_vector_type(4)));
typedef unsigned short u16;
typedef unsigned int   u32;
typedef unsigned long long u64;
#define SENT (~0ull)

__device__ __forceinline__ u16 f2bf(float x) {
    u32 u = __float_as_uint(x);
    u += 0x7FFFu + ((u >> 16) & 1u);
    return (u16)(u >> 16);
}
__device__ __forceinline__ float sigf(float x) { return 1.0f / (1.0f + __expf(-x)); }
__device__ __forceinline__ float tanh_fast(float x) {
    float ax = fabsf(x);
    float e = __expf(-2.0f * ax);
    return copysignf((1.0f - e) / (1.0f + e), x);
}
__device__ __forceinline__ u32 pk2f(float a, float b) {
    return (u32)f2bf(a) | ((u32)f2bf(b) << 16);
}

union bf8u { u32 u[4]; bf16x8 v; };

#define BARRIER() do { asm volatile("" ::: "memory"); \
                       __builtin_amdgcn_s_barrier(); \
                       asm volatile("" ::: "memory"); \
                       __builtin_amdgcn_sched_barrier(0); } while (0)
#define WAIT_LGKM() do { asm volatile("s_waitcnt lgkmcnt(0)" ::: "memory"); \
                         __builtin_amdgcn_sched_barrier(0); } while (0)
#define WAIT_VM()   do { asm volatile("s_waitcnt vmcnt(0)" ::: "memory"); \
                         __builtin_amdgcn_sched_barrier(0); } while (0)

#define MFMA16(a, b, c) __builtin_amdgcn_mfma_f32_16x16x32_bf16((a), (b), (c), 0, 0, 0)

__global__ void __launch_bounds__(512, 1)
mdn_kernel(const float* __restrict__ inp, const float* __restrict__ Wk,
           const float* __restrict__ Wr,  const float* __restrict__ bg,
           const float* __restrict__ Wd,  const float* __restrict__ bd,
           float* __restrict__ out, u64* __restrict__ hbuf)
{
    __shared__ __attribute__((aligned(16))) u16  wr_s[64 * HH];   // dead after preamble
    __shared__ __attribute__((aligned(16))) u16  wk_s[64 * 64];   // dead after preamble
    __shared__ __attribute__((aligned(16))) u16  wd_s[16 * HH];   // dead after preamble
    __shared__ __attribute__((aligned(16))) u16  hsA[GB * HH];    // h double buffer A
    __shared__ __attribute__((aligned(16))) u16  hsB[GB * HH];    // h double buffer B
    __shared__ __attribute__((aligned(16))) float gbuf[4 * 16 * GSTR];      // [w][batch][c]
    __shared__ __attribute__((aligned(16))) float pbuf[2 * 4 * 16 * GSTR];  // [par][kw][batch][oo]

    const int tid  = threadIdx.x;
    const int lane = tid & 63;
    const int wave = tid >> 6;
    const int g    = blockIdx.x & 7;    // batch group (XCD-affine under round-robin)
    const int s    = blockIdx.x >> 3;   // h-slice 0..31
    const int m16  = lane & 15;
    const int kq   = lane >> 4;

    // ---------------- preamble: weight staging + hsA zero ----------------
    {
        int n = tid & 63;
        int q = n >> 4, j4 = n & 15;
        int col = q * HH + s * 16 + j4;
        for (int k = tid >> 6; k < HH; k += 8)
            wr_s[n * HH + (k ^ ((n & 7) << 3))] = f2bf(Wr[(size_t)k * 2048 + col]);
        for (int k = tid >> 6; k < 64; k += 8)
            wk_s[n * 64 + (k ^ ((n & 7) << 3))] = f2bf(k < DIN ? Wk[(size_t)k * 2048 + col] : 0.0f);
    }
    {
        int n = tid & 15;
        for (int k = tid >> 4; k < HH; k += 32)
            wd_s[n * HH + (k ^ ((n & 7) << 3))] =
                f2bf(n < ODC ? Wd[(size_t)k * OUTC + s * ODC + n] : 0.0f);
    }
    for (int i = tid; i < GB * HH / 4; i += 512) ((u64*)hsA)[i] = 0ull;  // h_{-1}=0
    __syncthreads();   // one-time full sync

    // ---------------- B-fragments to registers (R11 gate-col mapping) ----------------
    bf16x8 bfr[18];
    if (wave < 4) {
        // wave owns hcols 4w..4w+3, all 4 gates: B-col m16 <-> (q=m16&3, e=m16>>2)
        int nloc = (m16 & 3) * 16 + 4 * wave + (m16 >> 2);   // local gate col 0..63
        #pragma unroll
        for (int ks = 0; ks < 16; ++ks) {
            int k0 = 32 * ks + 8 * kq;
            bfr[ks] = *(const bf16x8*)(&wr_s[nloc * HH + (k0 ^ ((nloc & 7) << 3))]);
        }
        #pragma unroll
        for (int i = 0; i < 2; ++i) {
            int k0 = 32 * i + 8 * kq;
            bfr[16 + i] = *(const bf16x8*)(&wk_s[nloc * 64 + (k0 ^ ((nloc & 7) << 3))]);
        }
    } else {
        int w4 = wave - 4;
        #pragma unroll
        for (int kk = 0; kk < 4; ++kk) {
            int k0 = w4 * 128 + 32 * kk + 8 * kq;
            bfr[kk] = *(const bf16x8*)(&wd_s[m16 * HH + (k0 ^ ((m16 & 7) << 3))]);
        }
    }

    // ---------------- per-lane state ----------------
    float c_reg = 0.f;
    float bi = 0.f, bff = 0.f, bgg = 0.f, boo = 0.f, bdv = 0.f;
    const int cb = lane & 15;          // gate waves: cell batch
    const int ce = lane >> 4;          // gate waves: cell hcol-in-wave (0..3)
    if (wave < 4) {
        int jj = 4 * wave + ce;        // cell hcol 0..15
        int scol = s * 16 + jj;
        bi  = bg[0 * HH + scol];
        bff = bg[1 * HH + scol];
        bgg = bg[2 * HH + scol];
        boo = bg[3 * HH + scol];
    } else {
        int oo = lane & 15;
        if (oo < ODC) bdv = bd[s * ODC + oo];
    }

    // x registers: gate lane (m16=batch, kq=k-section) owns x[m16][kq*8..+7] (+32..34, kq==0)
    float xr[8];
    float xe0 = 0.f, xe1 = 0.f, xe2 = 0.f;
    #pragma unroll
    for (int i = 0; i < 8; ++i) xr[i] = 0.f;
    if (wave < 4) {
        const float* ip = inp + ((size_t)(g * GB + m16) * TT + 0) * DIN;
        #pragma unroll
        for (int i = 0; i < 8; ++i) xr[i] = ip[kq * 8 + i];
        if (kq == 0) { xe0 = ip[32]; xe1 = ip[33]; xe2 = ip[34]; }
    }
    __syncthreads();

    for (int t = 0; t <= TT + 1; ++t) {
        // invariant at top: hs_cur = h_{t-1}; xr = x_t (gate waves)
        u16* hs_cur = (t & 1) ? hsB : hsA;
        u16* hs_nxt = (t & 1) ? hsA : hsB;

        if (wave < 4) {
            if (t < TT) {
                // ---- sentinel-reset own words of buf[(t+1)%3] (dead h_{t-2}) ----
                if (ce == 0) {
                    u64* rp = hbuf + (size_t)((t + 1) % 3) * (NGRP * HWORDS) + g * HWORDS
                                  + s * 64 + wave * 16 + cb;
                    __hip_atomic_store(rp, SENT, __ATOMIC_RELAXED, __HIP_MEMORY_SCOPE_AGENT);
                }
                // ---- gate MFMA ----
                bf8u a0, a1;
                a0.u[0] = pk2f(xr[0], xr[1]); a0.u[1] = pk2f(xr[2], xr[3]);
                a0.u[2] = pk2f(xr[4], xr[5]); a0.u[3] = pk2f(xr[6], xr[7]);
                a1.u[0] = (kq == 0) ? pk2f(xe0, xe1) : 0u;
                a1.u[1] = (kq == 0) ? pk2f(xe2, 0.f) : 0u;
                a1.u[2] = 0u; a1.u[3] = 0u;
                f32x4 acc0 = {0,0,0,0}, acc1 = {0,0,0,0};
                acc0 = MFMA16(a0.v, bfr[16], acc0);
                acc1 = MFMA16(a1.v, bfr[17], acc1);
                #pragma unroll
                for (int ks = 0; ks < 16; ks += 2) {
                    int k0 = 32 * ks + 8 * kq;
                    bf16x8 a = *(const bf16x8*)(&hs_cur[m16 * HH + (k0 ^ ((m16 & 7) << 3))]);
                    acc0 = MFMA16(a, bfr[ks], acc0);
                    int k1 = 32 * (ks + 1) + 8 * kq;
                    bf16x8 a2 = *(const bf16x8*)(&hs_cur[m16 * HH + (k1 ^ ((m16 & 7) << 3))]);
                    acc1 = MFMA16(a2, bfr[ks + 1], acc1);
                }
                // ---- same-wave D roundtrip ----
                #pragma unroll
                for (int j = 0; j < 4; ++j)
                    gbuf[wave * 16 * GSTR + (kq * 4 + j) * GSTR + m16] = acc0[j] + acc1[j];
                WAIT_LGKM();
                f32x4 gv = *(const f32x4*)(&gbuf[wave * 16 * GSTR + cb * GSTR + 4 * ce]);
                // ---- scalar LSTM cell ----
                float iv = gv[0] + bi, fv = gv[1] + bff;
                float gg2 = gv[2] + bgg, ov = gv[3] + boo;
                c_reg = sigf(fv) * c_reg + sigf(iv) * tanh_fast(gg2);
                float h = sigf(ov) * tanh_fast(c_reg);
                // ---- pack 4 hcols; drain (resets ack'd under MFMA); publish ----
                u32 hb32 = (u32)f2bf(h);
                u32 o1 = (u32)__shfl_xor((int)hb32, 16);
                u32 pair = ((ce & 1) == 0) ? (hb32 | (o1 << 16)) : (o1 | (hb32 << 16));
                u32 o2 = (u32)__shfl_xor((int)pair, 32);
                WAIT_VM();                          // orders prior resets < this publish
                if (ce == 0) {
                    u64 w64 = (u64)pair | ((u64)o2 << 32);   // hcols 4w..4w+3
                    u64* dst = hbuf + (size_t)(t % 3) * (NGRP * HWORDS) + g * HWORDS
                                  + s * 64 + wave * 16 + cb;  // full-line slice-major
                    __hip_atomic_store(dst, w64, __ATOMIC_RELAXED, __HIP_MEMORY_SCOPE_AGENT);
                }
                // x(t+1) prefetch (rides across barriers)
                if (t + 1 < TT) {
                    const float* ip = inp + ((size_t)(g * GB + m16) * TT + (t + 1)) * DIN;
                    #pragma unroll
                    for (int i = 0; i < 8; ++i) xr[i] = ip[kq * 8 + i];
                    if (kq == 0) { xe0 = ip[32]; xe1 = ip[33]; xe2 = ip[34]; }
                }
            }
        } else {
            int w4 = wave - 4;
            if (t >= 2) {
                // ---- reduce + store row t-2 from pbuf[prev] (barrier-ordered) ----
                int bb = 4 * w4 + (lane >> 4);
                int oo = lane & 15;
                int par = ((t & 1) ^ 1) * 4 * 16 * GSTR;
                float v = pbuf[par + 0 * 16 * GSTR + bb * GSTR + oo]
                        + pbuf[par + 1 * 16 * GSTR + bb * GSTR + oo]
                        + pbuf[par + 2 * 16 * GSTR + bb * GSTR + oo]
                        + pbuf[par + 3 * 16 * GSTR + bb * GSTR + oo] + bdv;
                if (oo < ODC)
                    out[((size_t)(g * GB + bb) * TT + (t - 2)) * OUTC + s * ODC + oo] = v;
            }
            if (t >= 1 && t <= TT) {
                // ---- out-GEMM partials row t-1 (hs_cur = h_{t-1}) -> pbuf[t&1] ----
                f32x4 acc0 = {0,0,0,0}, acc1 = {0,0,0,0};
                #pragma unroll
                for (int kk = 0; kk < 4; kk += 2) {
                    int k0 = w4 * 128 + 32 * kk + 8 * kq;
                    bf16x8 a = *(const bf16x8*)(&hs_cur[m16 * HH + (k0 ^ ((m16 & 7) << 3))]);
                    acc0 = MFMA16(a, bfr[kk], acc0);
                    int k1 = w4 * 128 + 32 * (kk + 1) + 8 * kq;
                    bf16x8 a2 = *(const bf16x8*)(&hs_cur[m16 * HH + (k1 ^ ((m16 & 7) << 3))]);
                    acc1 = MFMA16(a2, bfr[kk + 1], acc1);
                }
                #pragma unroll
                for (int j = 0; j < 4; ++j)
                    pbuf[(t & 1) * 4 * 16 * GSTR + w4 * 16 * GSTR + (kq * 4 + j) * GSTR + m16]
                        = acc0[j] + acc1[j];
            }
        }

        // ========== exchange: poll own 4 data words -> hs_nxt; ONE barrier ==========
        if (t < TT) {
            const u64* bp = hbuf + (size_t)(t % 3) * (NGRP * HWORDS) + g * HWORDS;
            const int L0 = tid, L1 = tid + 512, L2 = tid + 1024, L3 = tid + 1536;
            u64 v0 = SENT, v1 = SENT, v2 = SENT, v3 = SENT;
            int spins = 0;
            while (true) {
                if (v0 == SENT) v0 = __hip_atomic_load(bp + L0, __ATOMIC_RELAXED, __HIP_MEMORY_SCOPE_AGENT);
                if (v1 == SENT) v1 = __hip_atomic_load(bp + L1, __ATOMIC_RELAXED, __HIP_MEMORY_SCOPE_AGENT);
                if (v2 == SENT) v2 = __hip_atomic_load(bp + L2, __ATOMIC_RELAXED, __HIP_MEMORY_SCOPE_AGENT);
                if (v3 == SENT) v3 = __hip_atomic_load(bp + L3, __ATOMIC_RELAXED, __HIP_MEMORY_SCOPE_AGENT);
                if (__all((int)(v0 != SENT && v1 != SENT && v2 != SENT && v3 != SENT))) break;
                if (++spins > (1 << 20)) break;            // bounded bail-out: no hangs
                __builtin_amdgcn_s_sleep(1);               // backoff EVERY round (R15 lesson)
            }
            // scatter into hs_nxt (OTHER buffer than the one read this step)
            {
                u64 vv[4] = {v0, v1, v2, v3};
                #pragma unroll
                for (int i = 0; i < 4; ++i) {
                    int L = tid + i * 512;
                    int b    = L & 15;
                    int kcol = (L >> 6) * 16 + 4 * ((L >> 4) & 3);
                    *(u64*)(&hs_nxt[b * HH + (kcol ^ ((b & 7) << 3))]) = vv[i];
                }
            }
            WAIT_LGKM(); BARRIER();                        // single barrier: hs_nxt ready
        } else {
            // tail steps (t = TT, TT+1): order pbuf handoff for delayed reduce
            WAIT_LGKM(); BARRIER();
        }
    }
}

extern "C" void kernel_launch(void* const* d_in, const int* in_sizes, int n_in,
                              void* d_out, int out_size, void* d_ws, size_t ws_size,
                              hipStream_t stream) {
    const float* inp = (const float*)d_in[0];
    const float* Wk  = (const float*)d_in[1];
    const float* Wr  = (const float*)d_in[2];
    const float* bg  = (const float*)d_in[3];
    const float* Wd  = (const float*)d_in[4];
    const float* bd  = (const float*)d_in[5];
    float* out = (float*)d_out;

    // ws: h exchange, 3 rotating buffers x 8 groups x 2048 u64 = 384 KB.
    // Memset 0xFF (sentinel) every launch: bf16 h values are never NaN, so
    // ~0ull words unambiguously mean "not yet written this launch".
    u64* hbuf = (u64*)d_ws;
    size_t zbytes = (size_t)3 * NGRP * HWORDS * sizeof(u64);
    hipMemsetAsync(d_ws, 0xFF, zbytes, stream);

    hipLaunchKernelGGL(mdn_kernel, dim3(NGRP * NSLICE), dim3(512), 0, stream,
                       inp, Wk, Wr, bg, Wd, bd, out, hbuf);
}